// Round 3
// baseline (141.241 us; speedup 1.0000x reference)
//
#include <hip/hip_runtime.h>

typedef __bf16 bf16x8 __attribute__((ext_vector_type(8)));
typedef __bf16 bf16x4 __attribute__((ext_vector_type(4)));
typedef float  f32x4  __attribute__((ext_vector_type(4)));
typedef float  f32x16 __attribute__((ext_vector_type(16)));

constexpr int B_ = 4, S_ = 1024, D_ = 768, N_ = 12, H_ = 64;
constexpr int BNSH = B_ * N_ * S_ * H_;   // 3,145,728
constexpr float SCALE2 = 0.18033688011f;  // (1/sqrt(64)) * log2(e): exp2 domain

__device__ __forceinline__ f32x4 mfma16(bf16x8 a, bf16x8 b, f32x4 c) {
    return __builtin_amdgcn_mfma_f32_16x16x32_bf16(a, b, c, 0, 0, 0);
}
__device__ __forceinline__ f32x16 mfma32(bf16x8 a, bf16x8 b, f32x16 c) {
    return __builtin_amdgcn_mfma_f32_32x32x16_bf16(a, b, c, 0, 0, 0);
}

// pack 2 f32 -> 1 dword of 2 bf16 (lo = a, hi = b)
__device__ __forceinline__ unsigned pkbf16(float a, float b) {
    unsigned r;
    asm("v_cvt_pk_bf16_f32 %0, %1, %2" : "=v"(r) : "v"(a), "v"(b));
    return r;
}

// async global->LDS, 16B per lane. HW dest = wave-uniform base + lane*16.
__device__ __forceinline__ void gload16(const __bf16* g, __bf16* l) {
    __builtin_amdgcn_global_load_lds(
        (const __attribute__((address_space(1))) unsigned int*)g,
        (__attribute__((address_space(3))) unsigned int*)l, 16, 0, 0);
}

// ---- LDS tile staging with 16B-chunk xor swizzle --------------------------
// Tiles are [rows][64] bf16. Global chunk (r, q) lands at LDS slot (r, q^(r&7)).
__device__ __forceinline__ void stage128x64(const __bf16* g, int ld, __bf16* lds,
                                            int wid, int lane) {
    #pragma unroll
    for (int i = 0; i < 4; ++i) {
        int cb = (wid * 4 + i) * 64;
        int chunk = cb + lane;
        int r = chunk >> 3, p = chunk & 7;
        int q = p ^ (r & 7);
        gload16(g + (size_t)r * ld + q * 8, lds + cb * 8);
    }
}
__device__ __forceinline__ void stage64x64(const __bf16* g, int ld, __bf16* lds,
                                           int wid, int lane) {
    #pragma unroll
    for (int i = 0; i < 2; ++i) {
        int cb = (wid * 2 + i) * 64;
        int chunk = cb + lane;
        int r = chunk >> 3, p = chunk & 7;
        int q = p ^ (r & 7);
        gload16(g + (size_t)r * ld + q * 8, lds + cb * 8);
    }
}
// 2-wave (128-thread) variant for the new attn blocks.
__device__ __forceinline__ void stage64x64_w2(const __bf16* g, int ld, __bf16* lds,
                                              int wid, int lane) {
    #pragma unroll
    for (int i = 0; i < 4; ++i) {
        int cb = (wid * 4 + i) * 64;
        int chunk = cb + lane;
        int r = chunk >> 3, p = chunk & 7;
        int q = p ^ (r & 7);
        gload16(g + (size_t)r * ld + q * 8, lds + cb * 8);
    }
}

// ---------------------------------------------------------------------------
// Fused prep: cast x -> bf16; transpose-cast W_QKV -> [2304][768]; W_O -> B^T.
// ---------------------------------------------------------------------------
__global__ __launch_bounds__(256) void prep_kernel(
    const float* __restrict__ x,
    const float* __restrict__ wq, const float* __restrict__ wk,
    const float* __restrict__ wv, const float* __restrict__ wo,
    __bf16* __restrict__ xb, __bf16* __restrict__ wt, __bf16* __restrict__ wot) {
    __shared__ __bf16 T[64][65];
    const int blk = blockIdx.x;
    const int tid = threadIdx.x;
    if (blk < 768) {
        int base = blk * 1024 + tid;
        #pragma unroll
        for (int i = 0; i < 4; ++i) {
            int idx = base + i * 256;
            float4 v = ((const float4*)x)[idx];
            bf16x4 o;
            o[0] = (__bf16)v.x; o[1] = (__bf16)v.y;
            o[2] = (__bf16)v.z; o[3] = (__bf16)v.w;
            ((bf16x4*)xb)[idx] = o;
        }
        return;
    }
    int rr = tid >> 4, c4 = (tid & 15) * 4;
    if (blk < 1200) {
        int t = blk - 768;
        int dt = t % 12, mh = t / 12;
        int mat = mh / 12, n = mh % 12;
        const float* in = (mat == 0 ? wq : mat == 1 ? wk : wv) + (size_t)n * 768 * 64;
        __bf16* outp = wt + (size_t)(mat * 768 + n * 64) * 768;
        int d0 = dt * 64;
        #pragma unroll
        for (int i = 0; i < 4; ++i) {
            int row = rr + 16 * i;
            float4 v = *(const float4*)&in[(size_t)(d0 + row) * 64 + c4];
            T[c4 + 0][row] = (__bf16)v.x;
            T[c4 + 1][row] = (__bf16)v.y;
            T[c4 + 2][row] = (__bf16)v.z;
            T[c4 + 3][row] = (__bf16)v.w;
        }
        __syncthreads();
        #pragma unroll
        for (int i = 0; i < 4; ++i) {
            int hrow = rr + 16 * i;
            bf16x4 o;
            o[0] = T[hrow][c4 + 0]; o[1] = T[hrow][c4 + 1];
            o[2] = T[hrow][c4 + 2]; o[3] = T[hrow][c4 + 3];
            *(bf16x4*)&outp[(size_t)hrow * 768 + d0 + c4] = o;
        }
    } else {
        int t = blk - 1200;
        int r0 = (t % 12) * 64, c0 = (t / 12) * 64;
        #pragma unroll
        for (int i = 0; i < 4; ++i) {
            int row = rr + 16 * i;
            float4 v = *(const float4*)&wo[(size_t)(r0 + row) * 768 + c0 + c4];
            T[c4 + 0][row] = (__bf16)v.x;
            T[c4 + 1][row] = (__bf16)v.y;
            T[c4 + 2][row] = (__bf16)v.z;
            T[c4 + 3][row] = (__bf16)v.w;
        }
        __syncthreads();
        #pragma unroll
        for (int i = 0; i < 4; ++i) {
            int crow = rr + 16 * i;
            bf16x4 o;
            o[0] = T[crow][c4 + 0]; o[1] = T[crow][c4 + 1];
            o[2] = T[crow][c4 + 2]; o[3] = T[crow][c4 + 3];
            *(bf16x4*)&wot[(size_t)(c0 + crow) * 768 + r0 + c4] = o;
        }
    }
}

// ---------------------------------------------------------------------------
// QKV GEMM: tile 128x64, BK=64, double-buffered (unchanged, 137.3us config).
// Writes Q (prescaled by SCALE2), K as [B,N,S,H]; V^T as [B,N,H,S].
// ---------------------------------------------------------------------------
__global__ __launch_bounds__(256) void qkv_gemm(
    const __bf16* __restrict__ xb, const __bf16* __restrict__ wtg,
    const float* __restrict__ bq, const float* __restrict__ bk,
    const float* __restrict__ bv,
    __bf16* __restrict__ Qb, __bf16* __restrict__ Kb, __bf16* __restrict__ Vtb) {
    __shared__ __bf16 As[2][128 * 64];
    __shared__ __bf16 Bs[2][64 * 64];
    const int m0 = blockIdx.x * 128;
    const int j0 = blockIdx.y * 64;
    const int tid = threadIdx.x, wid = tid >> 6, lane = tid & 63;
    const int quad = lane >> 4, lrow = lane & 15;
    const int l3 = lrow & 7;
    int koff[2];
    #pragma unroll
    for (int ks = 0; ks < 2; ++ks)
        koff[ks] = lrow * 64 + ((ks * 4 + quad) ^ l3) * 8;

    f32x4 zf = {0.f, 0.f, 0.f, 0.f};
    f32x4 acc[2][4];
    #pragma unroll
    for (int i = 0; i < 2; ++i)
        #pragma unroll
        for (int j = 0; j < 4; ++j) acc[i][j] = zf;

    stage128x64(xb + (size_t)m0 * 768, 768, As[0], wid, lane);
    stage64x64(wtg + (size_t)j0 * 768, 768, Bs[0], wid, lane);

    for (int kt = 0; kt < 12; ++kt) {
        const int buf = kt & 1;
        __syncthreads();
        if (kt < 11) {
            stage128x64(xb + (size_t)m0 * 768 + (kt + 1) * 64, 768, As[buf ^ 1], wid, lane);
            stage64x64(wtg + (size_t)j0 * 768 + (kt + 1) * 64, 768, Bs[buf ^ 1], wid, lane);
        }
        #pragma unroll
        for (int ks = 0; ks < 2; ++ks) {
            bf16x8 af[2], bfr[4];
            #pragma unroll
            for (int mi = 0; mi < 2; ++mi)
                af[mi] = *(const bf16x8*)(As[buf] + (wid * 32 + mi * 16) * 64 + koff[ks]);
            #pragma unroll
            for (int ni = 0; ni < 4; ++ni)
                bfr[ni] = *(const bf16x8*)(Bs[buf] + ni * 1024 + koff[ks]);
            #pragma unroll
            for (int mi = 0; mi < 2; ++mi)
                #pragma unroll
                for (int ni = 0; ni < 4; ++ni)
                    acc[mi][ni] = mfma16(af[mi], bfr[ni], acc[mi][ni]);
        }
    }

    const int mat = j0 / 768;
    const int n = (j0 % 768) >> 6;
    const int b = m0 >> 10;
    const int s_base = (m0 & 1023) + wid * 32;
    const float* bias = (mat == 0 ? bq : mat == 1 ? bk : bv) + n * 64;
    const float osc = (mat == 0) ? SCALE2 : 1.0f;
    float bias_v[4];
    #pragma unroll
    for (int ni = 0; ni < 4; ++ni) bias_v[ni] = bias[ni * 16 + lrow];

    if (mat == 2) {
        __bf16* vout = Vtb + (size_t)(b * N_ + n) * 64 * 1024;
        #pragma unroll
        for (int mi = 0; mi < 2; ++mi)
            #pragma unroll
            for (int ni = 0; ni < 4; ++ni) {
                int h = ni * 16 + lrow;
                int s0 = s_base + mi * 16 + quad * 4;
                bf16x4 pv;
                #pragma unroll
                for (int r = 0; r < 4; ++r)
                    pv[r] = (__bf16)(acc[mi][ni][r] + bias_v[ni]);
                *(bf16x4*)(vout + (size_t)h * 1024 + s0) = pv;
            }
    } else {
        __bf16* qk = (mat == 0 ? Qb : Kb) + (size_t)(b * N_ + n) * 1024 * 64;
        #pragma unroll
        for (int mi = 0; mi < 2; ++mi)
            #pragma unroll
            for (int r = 0; r < 4; ++r) {
                int s = s_base + mi * 16 + quad * 4 + r;
                #pragma unroll
                for (int ni = 0; ni < 4; ++ni)
                    qk[(size_t)s * 64 + ni * 16 + lrow] =
                        (__bf16)((acc[mi][ni][r] + bias_v[ni]) * osc);
            }
    }
}

// ---------------------------------------------------------------------------
// Flash attention v9 — 32x32x16 MFMA, 2-wave blocks, in-register P (T12).
// Each wave owns a 32-q column half. QK^T: S^T[64s][32q] = K·Q^T (2 s-blocks
// x 4 k-steps). C-layout: col=lane&31 (=q), row=(reg&3)+8*(reg>>2)+4*(lane>>5)
// -> each lane holds 32 scores of ONE q column; no-max softmax stays lane-
// local. PV B-operand built in-register: per k-step, 4 cvt_pk + 2
// permlane32_swap give P^T[k-slice][q] (dest lane (q,hi) needs regs
// (j&3)+8(kk&1)+4hi from source half j>>2 -- exactly the swap's two outputs).
// Eliminates the Pt LDS strip and the 4x redundant K/V fragment reads of the
// 4-wave 16x16 version (72 -> 32 b128 per block-tile).
// ---------------------------------------------------------------------------
__global__ __launch_bounds__(128) void attn_mfma(
    const __bf16* __restrict__ Qb, const __bf16* __restrict__ Kb,
    const __bf16* __restrict__ Vtb, __bf16* __restrict__ zb) {
    __shared__ __bf16 Ks[2][64 * 64], Vs[2][64 * 64];
    const int bid = blockIdx.x;
    const int qt = 15 - bid / 48;          // longest-first
    const int bn = bid % 48;
    const int b = bn / N_, n = bn % N_;
    const int tid = threadIdx.x, wid = tid >> 6, lane = tid & 63;
    const int col = lane & 31;             // q within wave's 32-col block
    const int hi  = lane >> 5;
    const int c7  = col & 7;
    const __bf16* Qg = Qb + (size_t)(b * N_ + n) * S_ * H_;
    const __bf16* Kg = Kb + (size_t)(b * N_ + n) * S_ * H_;
    const __bf16* Vg = Vtb + (size_t)(b * N_ + n) * H_ * S_;
    const int q0 = qt * 64;
    const int qloc = wid * 32 + col;       // q local to tile

    // Q B-frags (prescaled by SCALE2): Q[q0+qloc][kk*16 + hi*8 + j]
    bf16x8 qf[4];
    #pragma unroll
    for (int kk = 0; kk < 4; ++kk)
        qf[kk] = *(const bf16x8*)&Qg[(size_t)(q0 + qloc) * 64 + kk * 16 + hi * 8];

    // LDS row bases for A-operand reads (row = b32*32 + col)
    int rowb[2];
    #pragma unroll
    for (int i = 0; i < 2; ++i) rowb[i] = (i * 32 + col) * 64;

    stage64x64_w2(Kg, 64, Ks[0], wid, lane);
    stage64x64_w2(Vg, 1024, Vs[0], wid, lane);

    const f32x16 zf16 = {0.f,0.f,0.f,0.f,0.f,0.f,0.f,0.f,
                         0.f,0.f,0.f,0.f,0.f,0.f,0.f,0.f};
    f32x16 o[2];
    o[0] = zf16; o[1] = zf16;
    float l_r = 0.f;

    auto do_tile = [&](int buf, bool diag) {
        // S^T = K·Q^T: sc[sb] covers s-rows sb*32..+31, cols = wave's 32 q
        f32x16 sc[2];
        sc[0] = zf16; sc[1] = zf16;
        __builtin_amdgcn_s_setprio(1);
        #pragma unroll
        for (int sb = 0; sb < 2; ++sb)
            #pragma unroll
            for (int kk = 0; kk < 4; ++kk) {
                bf16x8 kf = *(const bf16x8*)(Ks[buf] + rowb[sb]
                                             + ((kk * 2 + hi) ^ c7) * 8);
                sc[sb] = mfma32(kf, qf[kk], sc[sb]);
            }
        __builtin_amdgcn_s_setprio(0);
        if (diag) {
            #pragma unroll
            for (int sb = 0; sb < 2; ++sb)
                #pragma unroll
                for (int r = 0; r < 16; ++r) {
                    int sl = sb * 32 + (r & 3) + 8 * (r >> 2) + 4 * hi;
                    if (sl > qloc) sc[sb][r] = -1e30f;
                }
        }
        // no-max softmax: P = exp2(s); per-lane partial column-sum
        float rs = 0.f;
        #pragma unroll
        for (int sb = 0; sb < 2; ++sb)
            #pragma unroll
            for (int r = 0; r < 16; ++r) {
                float p = __builtin_amdgcn_exp2f(sc[sb][r]);
                sc[sb][r] = p;
                rs += p;
            }
        l_r += rs;
        // P^T B-frags fully in-register: per kk, 4 cvt_pk + 2 permlane32_swap
        bf16x8 pf[4];
        #pragma unroll
        for (int kk = 0; kk < 4; ++kk) {
            const int sb = kk >> 1, base = (kk & 1) * 8;
            unsigned A0 = pkbf16(sc[sb][base + 0], sc[sb][base + 1]);
            unsigned A1 = pkbf16(sc[sb][base + 2], sc[sb][base + 3]);
            unsigned B0 = pkbf16(sc[sb][base + 4], sc[sb][base + 5]);
            unsigned B1 = pkbf16(sc[sb][base + 6], sc[sb][base + 7]);
            asm volatile("v_permlane32_swap_b32 %0, %1" : "+v"(A0), "+v"(B0));
            asm volatile("v_permlane32_swap_b32 %0, %1" : "+v"(A1), "+v"(B1));
            union { unsigned w[4]; bf16x8 v; } u;
            u.w[0] = A0; u.w[1] = A1; u.w[2] = B0; u.w[3] = B1;
            pf[kk] = u.v;
        }
        // PV: O^T[h][q] += V^T[h][s] · P^T[s][q]
        __builtin_amdgcn_s_setprio(1);
        #pragma unroll
        for (int hb = 0; hb < 2; ++hb)
            #pragma unroll
            for (int kk = 0; kk < 4; ++kk) {
                bf16x8 vf = *(const bf16x8*)(Vs[buf] + rowb[hb]
                                             + ((kk * 2 + hi) ^ c7) * 8);
                o[hb] = mfma32(vf, pf[kk], o[hb]);
            }
        __builtin_amdgcn_s_setprio(0);
    };

    for (int kt = 0; kt < qt; ++kt) {
        __syncthreads();
        stage64x64_w2(Kg + (size_t)(kt + 1) * 64 * 64, 64, Ks[(kt + 1) & 1], wid, lane);
        stage64x64_w2(Vg + (kt + 1) * 64, 1024, Vs[(kt + 1) & 1], wid, lane);
        do_tile(kt & 1, false);
    }
    __syncthreads();
    do_tile(qt & 1, true);

    // epilogue: complementary s-rows of this q live in lane^32
    float lt = l_r + __shfl_xor(l_r, 32);
    const float linv = 1.0f / lt;
    __bf16* zout = zb + (size_t)b * S_ * 768 + (size_t)(q0 + qloc) * 768 + n * 64;
    #pragma unroll
    for (int hb = 0; hb < 2; ++hb)
        #pragma unroll
        for (int rq = 0; rq < 4; ++rq) {
            bf16x4 zo;
            #pragma unroll
            for (int j = 0; j < 4; ++j)
                zo[j] = (__bf16)(o[hb][rq * 4 + j] * linv);
            *(bf16x4*)&zout[hb * 32 + rq * 8 + hi * 4] = zo;
        }
}

// ---------------------------------------------------------------------------
// Output projection: tile 64x64, BK=64, double-buffered. Grid 768 blocks
// (3 blocks/CU vs 1.5 at 128x64 -- these short-K GEMMs are occupancy-bound).
// ---------------------------------------------------------------------------
__global__ __launch_bounds__(256) void out_gemm(
    const __bf16* __restrict__ zb, const __bf16* __restrict__ wot,
    const float* __restrict__ bo, float* __restrict__ out) {
    __shared__ __bf16 As[2][64 * 64];
    __shared__ __bf16 Bs[2][64 * 64];
    const int m0 = blockIdx.x * 64;
    const int j0 = blockIdx.y * 64;
    const int tid = threadIdx.x, wid = tid >> 6, lane = tid & 63;
    const int quad = lane >> 4, lrow = lane & 15;
    const int l3 = lrow & 7;
    int koff[2];
    #pragma unroll
    for (int ks = 0; ks < 2; ++ks)
        koff[ks] = lrow * 64 + ((ks * 4 + quad) ^ l3) * 8;

    f32x4 zf = {0.f, 0.f, 0.f, 0.f};
    f32x4 acc[4];
    #pragma unroll
    for (int j = 0; j < 4; ++j) acc[j] = zf;

    stage64x64(zb + (size_t)m0 * 768, 768, As[0], wid, lane);
    stage64x64(wot + (size_t)j0 * 768, 768, Bs[0], wid, lane);

    for (int kt = 0; kt < 12; ++kt) {
        const int buf = kt & 1;
        __syncthreads();
        if (kt < 11) {
            stage64x64(zb + (size_t)m0 * 768 + (kt + 1) * 64, 768, As[buf ^ 1], wid, lane);
            stage64x64(wot + (size_t)j0 * 768 + (kt + 1) * 64, 768, Bs[buf ^ 1], wid, lane);
        }
        #pragma unroll
        for (int ks = 0; ks < 2; ++ks) {
            bf16x8 af = *(const bf16x8*)(As[buf] + wid * 1024 + koff[ks]);
            #pragma unroll
            for (int ni = 0; ni < 4; ++ni) {
                bf16x8 bfr = *(const bf16x8*)(Bs[buf] + ni * 1024 + koff[ks]);
                acc[ni] = mfma16(af, bfr, acc[ni]);
            }
        }
    }

    float bias_v[4];
    #pragma unroll
    for (int ni = 0; ni < 4; ++ni) bias_v[ni] = bo[j0 + ni * 16 + lrow];
    #pragma unroll
    for (int r = 0; r < 4; ++r) {
        int m = m0 + wid * 16 + quad * 4 + r;
        #pragma unroll
        for (int ni = 0; ni < 4; ++ni)
            out[(size_t)m * 768 + j0 + ni * 16 + lrow] = acc[ni][r] + bias_v[ni];
    }
}

// ---------------------------------------------------------------------------
extern "C" void kernel_launch(void* const* d_in, const int* in_sizes, int n_in,
                              void* d_out, int out_size, void* d_ws, size_t ws_size,
                              hipStream_t stream) {
    const float* x  = (const float*)d_in[0];
    const float* wq = (const float*)d_in[1];
    const float* wk = (const float*)d_in[2];
    const float* wv = (const float*)d_in[3];
    const float* wo = (const float*)d_in[4];
    const float* bq = (const float*)d_in[5];
    const float* bk = (const float*)d_in[6];
    const float* bv = (const float*)d_in[7];
    const float* bo = (const float*)d_in[8];
    float* out = (float*)d_out;

    __bf16* p   = (__bf16*)d_ws;
    __bf16* xb  = p;  p += (size_t)4096 * 768;
    __bf16* wt  = p;  p += (size_t)2304 * 768;
    __bf16* wot = p;  p += (size_t)768 * 768;
    __bf16* Qb  = p;  p += (size_t)BNSH;
    __bf16* Kb  = p;  p += (size_t)BNSH;
    __bf16* Vtb = p;  p += (size_t)BNSH;
    __bf16* zb  = p;  p += (size_t)4096 * 768;

    prep_kernel<<<1344, 256, 0, stream>>>(x, wq, wk, wv, wo, xb, wt, wot);
    qkv_gemm<<<dim3(32, 36), 256, 0, stream>>>(xb, wt, bq, bk, bv, Qb, Kb, Vtb);
    attn_mfma<<<768, 128, 0, stream>>>(Qb, Kb, Vtb, zb);
    out_gemm<<<dim3(64, 12), 256, 0, stream>>>(zb, wot, bo, out);
}

// Round 4
// 140.106 us; speedup vs baseline: 1.0081x; 1.0081x over previous
//
#include <hip/hip_runtime.h>

typedef __bf16 bf16x8 __attribute__((ext_vector_type(8)));
typedef __bf16 bf16x4 __attribute__((ext_vector_type(4)));
typedef float  f32x4  __attribute__((ext_vector_type(4)));
typedef float  f32x16 __attribute__((ext_vector_type(16)));

constexpr int B_ = 4, S_ = 1024, D_ = 768, N_ = 12, H_ = 64;
constexpr int BNSH = B_ * N_ * S_ * H_;   // 3,145,728
constexpr float SCALE2 = 0.18033688011f;  // (1/sqrt(64)) * log2(e): exp2 domain

__device__ __forceinline__ f32x4 mfma16(bf16x8 a, bf16x8 b, f32x4 c) {
    return __builtin_amdgcn_mfma_f32_16x16x32_bf16(a, b, c, 0, 0, 0);
}
__device__ __forceinline__ f32x16 mfma32(bf16x8 a, bf16x8 b, f32x16 c) {
    return __builtin_amdgcn_mfma_f32_32x32x16_bf16(a, b, c, 0, 0, 0);
}

// pack 2 f32 -> 1 dword of 2 bf16 (lo = a, hi = b)
__device__ __forceinline__ unsigned pkbf16(float a, float b) {
    unsigned r;
    asm("v_cvt_pk_bf16_f32 %0, %1, %2" : "=v"(r) : "v"(a), "v"(b));
    return r;
}

// async global->LDS, 16B per lane. HW dest = wave-uniform base + lane*16.
__device__ __forceinline__ void gload16(const __bf16* g, __bf16* l) {
    __builtin_amdgcn_global_load_lds(
        (const __attribute__((address_space(1))) unsigned int*)g,
        (__attribute__((address_space(3))) unsigned int*)l, 16, 0, 0);
}

// ---- LDS tile staging with 16B-chunk xor swizzle --------------------------
// Tiles are [rows][64] bf16. Global chunk (r, q) lands at LDS slot (r, q^(r&7)).
__device__ __forceinline__ void stage128x64(const __bf16* g, int ld, __bf16* lds,
                                            int wid, int lane) {
    #pragma unroll
    for (int i = 0; i < 4; ++i) {
        int cb = (wid * 4 + i) * 64;
        int chunk = cb + lane;
        int r = chunk >> 3, p = chunk & 7;
        int q = p ^ (r & 7);
        gload16(g + (size_t)r * ld + q * 8, lds + cb * 8);
    }
}
__device__ __forceinline__ void stage64x64(const __bf16* g, int ld, __bf16* lds,
                                           int wid, int lane) {
    #pragma unroll
    for (int i = 0; i < 2; ++i) {
        int cb = (wid * 2 + i) * 64;
        int chunk = cb + lane;
        int r = chunk >> 3, p = chunk & 7;
        int q = p ^ (r & 7);
        gload16(g + (size_t)r * ld + q * 8, lds + cb * 8);
    }
}

// ---------------------------------------------------------------------------
// Fused prep: cast x -> bf16; transpose-cast W_QKV -> [2304][768]; W_O -> B^T.
// ---------------------------------------------------------------------------
__global__ __launch_bounds__(256) void prep_kernel(
    const float* __restrict__ x,
    const float* __restrict__ wq, const float* __restrict__ wk,
    const float* __restrict__ wv, const float* __restrict__ wo,
    __bf16* __restrict__ xb, __bf16* __restrict__ wt, __bf16* __restrict__ wot) {
    __shared__ __bf16 T[64][65];
    const int blk = blockIdx.x;
    const int tid = threadIdx.x;
    if (blk < 768) {
        int base = blk * 1024 + tid;
        #pragma unroll
        for (int i = 0; i < 4; ++i) {
            int idx = base + i * 256;
            float4 v = ((const float4*)x)[idx];
            bf16x4 o;
            o[0] = (__bf16)v.x; o[1] = (__bf16)v.y;
            o[2] = (__bf16)v.z; o[3] = (__bf16)v.w;
            ((bf16x4*)xb)[idx] = o;
        }
        return;
    }
    int rr = tid >> 4, c4 = (tid & 15) * 4;
    if (blk < 1200) {
        int t = blk - 768;
        int dt = t % 12, mh = t / 12;
        int mat = mh / 12, n = mh % 12;
        const float* in = (mat == 0 ? wq : mat == 1 ? wk : wv) + (size_t)n * 768 * 64;
        __bf16* outp = wt + (size_t)(mat * 768 + n * 64) * 768;
        int d0 = dt * 64;
        #pragma unroll
        for (int i = 0; i < 4; ++i) {
            int row = rr + 16 * i;
            float4 v = *(const float4*)&in[(size_t)(d0 + row) * 64 + c4];
            T[c4 + 0][row] = (__bf16)v.x;
            T[c4 + 1][row] = (__bf16)v.y;
            T[c4 + 2][row] = (__bf16)v.z;
            T[c4 + 3][row] = (__bf16)v.w;
        }
        __syncthreads();
        #pragma unroll
        for (int i = 0; i < 4; ++i) {
            int hrow = rr + 16 * i;
            bf16x4 o;
            o[0] = T[hrow][c4 + 0]; o[1] = T[hrow][c4 + 1];
            o[2] = T[hrow][c4 + 2]; o[3] = T[hrow][c4 + 3];
            *(bf16x4*)&outp[(size_t)hrow * 768 + d0 + c4] = o;
        }
    } else {
        int t = blk - 1200;
        int r0 = (t % 12) * 64, c0 = (t / 12) * 64;
        #pragma unroll
        for (int i = 0; i < 4; ++i) {
            int row = rr + 16 * i;
            float4 v = *(const float4*)&wo[(size_t)(r0 + row) * 768 + c0 + c4];
            T[c4 + 0][row] = (__bf16)v.x;
            T[c4 + 1][row] = (__bf16)v.y;
            T[c4 + 2][row] = (__bf16)v.z;
            T[c4 + 3][row] = (__bf16)v.w;
        }
        __syncthreads();
        #pragma unroll
        for (int i = 0; i < 4; ++i) {
            int crow = rr + 16 * i;
            bf16x4 o;
            o[0] = T[crow][c4 + 0]; o[1] = T[crow][c4 + 1];
            o[2] = T[crow][c4 + 2]; o[3] = T[crow][c4 + 3];
            *(bf16x4*)&wot[(size_t)(c0 + crow) * 768 + r0 + c4] = o;
        }
    }
}

// ---------------------------------------------------------------------------
// QKV GEMM: tile 128x64, BK=64, double-buffered (unchanged, 137.3us config).
// Writes Q (prescaled by SCALE2), K as [B,N,S,H]; V^T as [B,N,H,S].
// ---------------------------------------------------------------------------
__global__ __launch_bounds__(256) void qkv_gemm(
    const __bf16* __restrict__ xb, const __bf16* __restrict__ wtg,
    const float* __restrict__ bq, const float* __restrict__ bk,
    const float* __restrict__ bv,
    __bf16* __restrict__ Qb, __bf16* __restrict__ Kb, __bf16* __restrict__ Vtb) {
    __shared__ __bf16 As[2][128 * 64];
    __shared__ __bf16 Bs[2][64 * 64];
    const int m0 = blockIdx.x * 128;
    const int j0 = blockIdx.y * 64;
    const int tid = threadIdx.x, wid = tid >> 6, lane = tid & 63;
    const int quad = lane >> 4, lrow = lane & 15;
    const int l3 = lrow & 7;
    int koff[2];
    #pragma unroll
    for (int ks = 0; ks < 2; ++ks)
        koff[ks] = lrow * 64 + ((ks * 4 + quad) ^ l3) * 8;

    f32x4 zf = {0.f, 0.f, 0.f, 0.f};
    f32x4 acc[2][4];
    #pragma unroll
    for (int i = 0; i < 2; ++i)
        #pragma unroll
        for (int j = 0; j < 4; ++j) acc[i][j] = zf;

    stage128x64(xb + (size_t)m0 * 768, 768, As[0], wid, lane);
    stage64x64(wtg + (size_t)j0 * 768, 768, Bs[0], wid, lane);

    for (int kt = 0; kt < 12; ++kt) {
        const int buf = kt & 1;
        __syncthreads();
        if (kt < 11) {
            stage128x64(xb + (size_t)m0 * 768 + (kt + 1) * 64, 768, As[buf ^ 1], wid, lane);
            stage64x64(wtg + (size_t)j0 * 768 + (kt + 1) * 64, 768, Bs[buf ^ 1], wid, lane);
        }
        #pragma unroll
        for (int ks = 0; ks < 2; ++ks) {
            bf16x8 af[2], bfr[4];
            #pragma unroll
            for (int mi = 0; mi < 2; ++mi)
                af[mi] = *(const bf16x8*)(As[buf] + (wid * 32 + mi * 16) * 64 + koff[ks]);
            #pragma unroll
            for (int ni = 0; ni < 4; ++ni)
                bfr[ni] = *(const bf16x8*)(Bs[buf] + ni * 1024 + koff[ks]);
            #pragma unroll
            for (int mi = 0; mi < 2; ++mi)
                #pragma unroll
                for (int ni = 0; ni < 4; ++ni)
                    acc[mi][ni] = mfma16(af[mi], bfr[ni], acc[mi][ni]);
        }
    }

    const int mat = j0 / 768;
    const int n = (j0 % 768) >> 6;
    const int b = m0 >> 10;
    const int s_base = (m0 & 1023) + wid * 32;
    const float* bias = (mat == 0 ? bq : mat == 1 ? bk : bv) + n * 64;
    const float osc = (mat == 0) ? SCALE2 : 1.0f;
    float bias_v[4];
    #pragma unroll
    for (int ni = 0; ni < 4; ++ni) bias_v[ni] = bias[ni * 16 + lrow];

    if (mat == 2) {
        __bf16* vout = Vtb + (size_t)(b * N_ + n) * 64 * 1024;
        #pragma unroll
        for (int mi = 0; mi < 2; ++mi)
            #pragma unroll
            for (int ni = 0; ni < 4; ++ni) {
                int h = ni * 16 + lrow;
                int s0 = s_base + mi * 16 + quad * 4;
                bf16x4 pv;
                #pragma unroll
                for (int r = 0; r < 4; ++r)
                    pv[r] = (__bf16)(acc[mi][ni][r] + bias_v[ni]);
                *(bf16x4*)(vout + (size_t)h * 1024 + s0) = pv;
            }
    } else {
        __bf16* qk = (mat == 0 ? Qb : Kb) + (size_t)(b * N_ + n) * 1024 * 64;
        #pragma unroll
        for (int mi = 0; mi < 2; ++mi)
            #pragma unroll
            for (int r = 0; r < 4; ++r) {
                int s = s_base + mi * 16 + quad * 4 + r;
                #pragma unroll
                for (int ni = 0; ni < 4; ++ni)
                    qk[(size_t)s * 64 + ni * 16 + lrow] =
                        (__bf16)((acc[mi][ni][r] + bias_v[ni]) * osc);
            }
    }
}

// ---------------------------------------------------------------------------
// Flash attention v10 — 32x32x16 + in-register P (v9, correctness-proven)
// + even/odd-kt wave-pair split to restore TLP (v9 regressed at 6 waves/CU).
// 4 waves: {0,1} compute even kt, {2,3} odd kt; both pairs cover q-cols
// {0-31, 32-63}. buf parity (kt&1) == computing-pair parity, so the double
// buffer needs no extra barriers; all 4 waves co-stage every tile (uniform
// trip count -> no divergent barriers). No-max softmax => split-kt partials
// merge by pure addition (no rescale), done in LDS at the end.
// 12 waves/CU restored with v9's halved MFMA count + 2.25x lower LDS reads.
// ---------------------------------------------------------------------------
__global__ __launch_bounds__(256) void attn_mfma(
    const __bf16* __restrict__ Qb, const __bf16* __restrict__ Kb,
    const __bf16* __restrict__ Vtb, __bf16* __restrict__ zb) {
    __shared__ __bf16 Ks[2][64 * 64], Vs[2][64 * 64];
    __shared__ float MS[2][64][33];        // merge scratch: [q-half][lane][o0..31,l]
    const int bid = blockIdx.x;
    const int qt = 15 - bid / 48;          // longest-first
    const int bn = bid % 48;
    const int b = bn / N_, n = bn % N_;
    const int tid = threadIdx.x, wid = tid >> 6, lane = tid & 63;
    const int wq = wid & 1;                // q-col half this wave owns
    const int wk = wid >> 1;               // kt parity this wave computes
    const int col = lane & 31;             // q within the 32-col block
    const int hi  = lane >> 5;
    const int c7  = col & 7;
    const __bf16* Qg = Qb + (size_t)(b * N_ + n) * S_ * H_;
    const __bf16* Kg = Kb + (size_t)(b * N_ + n) * S_ * H_;
    const __bf16* Vg = Vtb + (size_t)(b * N_ + n) * H_ * S_;
    const int q0 = qt * 64;
    const int qloc = wq * 32 + col;        // q local to tile

    // Q B-frags (prescaled by SCALE2): Q[q0+qloc][kk*16 + hi*8 + j]
    bf16x8 qf[4];
    #pragma unroll
    for (int kk = 0; kk < 4; ++kk)
        qf[kk] = *(const bf16x8*)&Qg[(size_t)(q0 + qloc) * 64 + kk * 16 + hi * 8];

    // LDS row bases for A-operand reads (row = blk32*32 + col)
    int rowb[2];
    #pragma unroll
    for (int i = 0; i < 2; ++i) rowb[i] = (i * 32 + col) * 64;

    stage64x64(Kg, 64, Ks[0], wid, lane);
    stage64x64(Vg, 1024, Vs[0], wid, lane);

    const f32x16 zf16 = {0.f,0.f,0.f,0.f,0.f,0.f,0.f,0.f,
                         0.f,0.f,0.f,0.f,0.f,0.f,0.f,0.f};
    f32x16 o[2];
    o[0] = zf16; o[1] = zf16;
    float l_r = 0.f;

    auto do_tile = [&](int buf, bool diag) {
        // S^T = K·Q^T: sc[sb] covers s-rows sb*32..+31, cols = wave's 32 q
        f32x16 sc[2];
        sc[0] = zf16; sc[1] = zf16;
        __builtin_amdgcn_s_setprio(1);
        #pragma unroll
        for (int sb = 0; sb < 2; ++sb)
            #pragma unroll
            for (int kk = 0; kk < 4; ++kk) {
                bf16x8 kf = *(const bf16x8*)(Ks[buf] + rowb[sb]
                                             + ((kk * 2 + hi) ^ c7) * 8);
                sc[sb] = mfma32(kf, qf[kk], sc[sb]);
            }
        __builtin_amdgcn_s_setprio(0);
        if (diag) {
            #pragma unroll
            for (int sb = 0; sb < 2; ++sb)
                #pragma unroll
                for (int r = 0; r < 16; ++r) {
                    int sl = sb * 32 + (r & 3) + 8 * (r >> 2) + 4 * hi;
                    if (sl > qloc) sc[sb][r] = -1e30f;
                }
        }
        // no-max softmax: P = exp2(s); per-lane partial column-sum
        float rs = 0.f;
        #pragma unroll
        for (int sb = 0; sb < 2; ++sb)
            #pragma unroll
            for (int r = 0; r < 16; ++r) {
                float p = __builtin_amdgcn_exp2f(sc[sb][r]);
                sc[sb][r] = p;
                rs += p;
            }
        l_r += rs;
        // P^T B-frags fully in-register: per kk, 4 cvt_pk + 2 permlane32_swap
        bf16x8 pf[4];
        #pragma unroll
        for (int kk = 0; kk < 4; ++kk) {
            const int sb = kk >> 1, base = (kk & 1) * 8;
            unsigned A0 = pkbf16(sc[sb][base + 0], sc[sb][base + 1]);
            unsigned A1 = pkbf16(sc[sb][base + 2], sc[sb][base + 3]);
            unsigned B0 = pkbf16(sc[sb][base + 4], sc[sb][base + 5]);
            unsigned B1 = pkbf16(sc[sb][base + 6], sc[sb][base + 7]);
            asm volatile("v_permlane32_swap_b32 %0, %1" : "+v"(A0), "+v"(B0));
            asm volatile("v_permlane32_swap_b32 %0, %1" : "+v"(A1), "+v"(B1));
            union { unsigned w[4]; bf16x8 v; } u;
            u.w[0] = A0; u.w[1] = A1; u.w[2] = B0; u.w[3] = B1;
            pf[kk] = u.v;
        }
        // PV: O^T[h][q] += V^T[h][s] · P^T[s][q]
        __builtin_amdgcn_s_setprio(1);
        #pragma unroll
        for (int hb = 0; hb < 2; ++hb)
            #pragma unroll
            for (int kk = 0; kk < 4; ++kk) {
                bf16x8 vf = *(const bf16x8*)(Vs[buf] + rowb[hb]
                                             + ((kk * 2 + hi) ^ c7) * 8);
                o[hb] = mfma32(vf, pf[kk], o[hb]);
            }
        __builtin_amdgcn_s_setprio(0);
    };

    const int nt = qt + 1;
    for (int kt = 0; kt < nt; ++kt) {
        __syncthreads();
        if (kt + 1 < nt) {
            stage64x64(Kg + (size_t)(kt + 1) * 64 * 64, 64, Ks[(kt + 1) & 1], wid, lane);
            stage64x64(Vg + (kt + 1) * 64, 1024, Vs[(kt + 1) & 1], wid, lane);
        }
        if ((kt & 1) == wk) do_tile(kt & 1, kt == qt);
    }

    // merge even/odd-kt partials: pure sum (no-max softmax => no rescale)
    __syncthreads();
    if (wk) {
        #pragma unroll
        for (int hb = 0; hb < 2; ++hb)
            #pragma unroll
            for (int r = 0; r < 16; ++r)
                MS[wq][lane][hb * 16 + r] = o[hb][r];
        MS[wq][lane][32] = l_r;
    }
    __syncthreads();
    if (!wk) {
        #pragma unroll
        for (int hb = 0; hb < 2; ++hb)
            #pragma unroll
            for (int r = 0; r < 16; ++r)
                o[hb][r] += MS[wq][lane][hb * 16 + r];
        l_r += MS[wq][lane][32];
        // complementary s-rows of this q live in lane^32
        float lt = l_r + __shfl_xor(l_r, 32);
        const float linv = 1.0f / lt;
        __bf16* zout = zb + (size_t)b * S_ * 768 + (size_t)(q0 + qloc) * 768 + n * 64;
        #pragma unroll
        for (int hb = 0; hb < 2; ++hb)
            #pragma unroll
            for (int rq = 0; rq < 4; ++rq) {
                bf16x4 zo;
                #pragma unroll
                for (int j = 0; j < 4; ++j)
                    zo[j] = (__bf16)(o[hb][rq * 4 + j] * linv);
                *(bf16x4*)&zout[hb * 32 + rq * 8 + hi * 4] = zo;
            }
    }
}

// ---------------------------------------------------------------------------
// Output projection: tile 64x64, BK=64, double-buffered. Grid 768 blocks
// (3 blocks/CU vs 1.5 at 128x64 -- these short-K GEMMs are occupancy-bound).
// ---------------------------------------------------------------------------
__global__ __launch_bounds__(256) void out_gemm(
    const __bf16* __restrict__ zb, const __bf16* __restrict__ wot,
    const float* __restrict__ bo, float* __restrict__ out) {
    __shared__ __bf16 As[2][64 * 64];
    __shared__ __bf16 Bs[2][64 * 64];
    const int m0 = blockIdx.x * 64;
    const int j0 = blockIdx.y * 64;
    const int tid = threadIdx.x, wid = tid >> 6, lane = tid & 63;
    const int quad = lane >> 4, lrow = lane & 15;
    const int l3 = lrow & 7;
    int koff[2];
    #pragma unroll
    for (int ks = 0; ks < 2; ++ks)
        koff[ks] = lrow * 64 + ((ks * 4 + quad) ^ l3) * 8;

    f32x4 zf = {0.f, 0.f, 0.f, 0.f};
    f32x4 acc[4];
    #pragma unroll
    for (int j = 0; j < 4; ++j) acc[j] = zf;

    stage64x64(zb + (size_t)m0 * 768, 768, As[0], wid, lane);
    stage64x64(wot + (size_t)j0 * 768, 768, Bs[0], wid, lane);

    for (int kt = 0; kt < 12; ++kt) {
        const int buf = kt & 1;
        __syncthreads();
        if (kt < 11) {
            stage64x64(zb + (size_t)m0 * 768 + (kt + 1) * 64, 768, As[buf ^ 1], wid, lane);
            stage64x64(wot + (size_t)j0 * 768 + (kt + 1) * 64, 768, Bs[buf ^ 1], wid, lane);
        }
        #pragma unroll
        for (int ks = 0; ks < 2; ++ks) {
            bf16x8 af = *(const bf16x8*)(As[buf] + wid * 1024 + koff[ks]);
            #pragma unroll
            for (int ni = 0; ni < 4; ++ni) {
                bf16x8 bfr = *(const bf16x8*)(Bs[buf] + ni * 1024 + koff[ks]);
                acc[ni] = mfma16(af, bfr, acc[ni]);
            }
        }
    }

    float bias_v[4];
    #pragma unroll
    for (int ni = 0; ni < 4; ++ni) bias_v[ni] = bo[j0 + ni * 16 + lrow];
    #pragma unroll
    for (int r = 0; r < 4; ++r) {
        int m = m0 + wid * 16 + quad * 4 + r;
        #pragma unroll
        for (int ni = 0; ni < 4; ++ni)
            out[(size_t)m * 768 + j0 + ni * 16 + lrow] = acc[ni][r] + bias_v[ni];
    }
}

// ---------------------------------------------------------------------------
extern "C" void kernel_launch(void* const* d_in, const int* in_sizes, int n_in,
                              void* d_out, int out_size, void* d_ws, size_t ws_size,
                              hipStream_t stream) {
    const float* x  = (const float*)d_in[0];
    const float* wq = (const float*)d_in[1];
    const float* wk = (const float*)d_in[2];
    const float* wv = (const float*)d_in[3];
    const float* wo = (const float*)d_in[4];
    const float* bq = (const float*)d_in[5];
    const float* bk = (const float*)d_in[6];
    const float* bv = (const float*)d_in[7];
    const float* bo = (const float*)d_in[8];
    float* out = (float*)d_out;

    __bf16* p   = (__bf16*)d_ws;
    __bf16* xb  = p;  p += (size_t)4096 * 768;
    __bf16* wt  = p;  p += (size_t)2304 * 768;
    __bf16* wot = p;  p += (size_t)768 * 768;
    __bf16* Qb  = p;  p += (size_t)BNSH;
    __bf16* Kb  = p;  p += (size_t)BNSH;
    __bf16* Vtb = p;  p += (size_t)BNSH;
    __bf16* zb  = p;  p += (size_t)4096 * 768;

    prep_kernel<<<1344, 256, 0, stream>>>(x, wq, wk, wv, wo, xb, wt, wot);
    qkv_gemm<<<dim3(32, 36), 256, 0, stream>>>(xb, wt, bq, bk, bv, Qb, Kb, Vtb);
    attn_mfma<<<768, 256, 0, stream>>>(Qb, Kb, Vtb, zb);
    out_gemm<<<dim3(64, 12), 256, 0, stream>>>(zb, wot, bo, out);
}